// Round 9
// baseline (664.826 us; speedup 1.0000x reference)
//
#include <hip/hip_runtime.h>
#include <stdint.h>

typedef unsigned long long u64;
typedef unsigned u32;

// ---------------------------------------------------------------------------
// RPN proposal generation (decode + per-level topk + NMS + final topk)
// ---------------------------------------------------------------------------

constexpr int NIMG = 16;
constexpr int NLVL = 5;
constexpr int ATOT = 261888;
__device__ constexpr int LVL_N[5]   = {196608, 49152, 12288, 3072, 768};
__device__ constexpr int LVL_OFF[5] = {0, 196608, 245760, 258048, 261120};
__device__ constexpr int LVL_K[5]   = {2000, 2000, 2000, 2000, 768};
__device__ constexpr int CAT_OFF[5] = {0, 2000, 4000, 6000, 8000};
constexpr int TOTK = 8768;          // 4*2000 + 768
constexpr int FINAL_K = 1000;
constexpr float NEGV = -1000000000.0f;
constexpr float CLIPV = 4.135166556742356f;   // log(1000/16)
constexpr float IMGSZ = 1024.0f;
constexpr float NMS_T = 0.7f;
constexpr int MAXK = 2000;
constexpr int MW   = 32;            // mask words per row (ceil(2000/64))
constexpr int MAXT = 528;           // 64x64 tiles per problem (W=32 upper triangle)

constexpr int NSLICE  = 65;         // per image: 48 + 12 + 3 + 1 + 1 (4096-item slices)
constexpr int NBIN    = 8192;       // 13-bit first-digit bins
constexpr int CANDCAP = 4096;       // per-problem candidate capacity

#define T_BLK 256

// ---------------- workspace layout (bytes) ----------------
constexpr size_t BOX_OFF    = 0;                                   // 16*8768*16
constexpr size_t SCORES_OFF = (size_t)NIMG * TOTK * 16;            // 2,244,608
constexpr size_t GHIST_OFF  = SCORES_OFF + (size_t)NIMG * TOTK * 4;// 2,805,760
constexpr size_t CNT_OFF    = GHIST_OFF + (size_t)NIMG * NLVL * NBIN * 4; // 5,427,200
constexpr size_t GB_OFF     = CNT_OFF + (size_t)NIMG * NLVL * 4;   // 5,427,520
constexpr size_t CAND_OFF   = GB_OFF + (size_t)NIMG * NLVL * 4;    // 5,427,840
constexpr size_t MASK_OFF   = ((CAND_OFF + (size_t)NIMG * NLVL * CANDCAP * 8) + 255) & ~(size_t)255;
constexpr size_t MASK_BYTES = (size_t)NIMG * NLVL * MAXK * MW * 8; // ~41 MB
constexpr int    ZERO_WORDS = NIMG * NLVL * NBIN + NIMG * NLVL;    // ghist + cand_cnt (contiguous)

// ordered-uint mapping: monotone with float value
__device__ inline unsigned ordf(float f) {
    unsigned u = __float_as_uint(f);
    return (u & 0x80000000u) ? ~u : (u | 0x80000000u);
}

__device__ inline u64 make_key(float sc, int idx) {
    return (((u64)ordf(sc)) << 32) | (u64)(0xFFFFFFFFu - (unsigned)idx);
}

// read a u64 VGPR pair from a (uniform) lane -> uniform scalar
__device__ inline u64 rl64(u64 v, int l) {
    u32 lo = (u32)__builtin_amdgcn_readlane((int)(u32)v, l);
    u32 hi = (u32)__builtin_amdgcn_readlane((int)(u32)(v >> 32), l);
    return (((u64)hi) << 32) | (u64)lo;
}

// decode + clip, faithful to reference float32 op order (no FMA contraction)
__device__ inline float4 decode_clip(const float4 an, const float4 dl) {
#pragma clang fp contract(off)
    float w  = an.z - an.x;
    float h  = an.w - an.y;
    float cx = an.x + 0.5f * w;
    float cy = an.y + 0.5f * h;
    float dw = fminf(dl.z, CLIPV);
    float dh = fminf(dl.w, CLIPV);
    float pcx = dl.x * w + cx;
    float pcy = dl.y * h + cy;
    float pw  = expf(dw) * w;
    float ph  = expf(dh) * h;
    float x1 = pcx - 0.5f * pw;
    float y1 = pcy - 0.5f * ph;
    float x2 = pcx + 0.5f * pw;
    float y2 = pcy + 0.5f * ph;
    x1 = fminf(fmaxf(x1, 0.0f), IMGSZ);
    x2 = fminf(fmaxf(x2, 0.0f), IMGSZ);
    y1 = fminf(fmaxf(y1, 0.0f), IMGSZ);
    y2 = fminf(fmaxf(y2, 0.0f), IMGSZ);
    return make_float4(x1, y1, x2, y2);
}

// IoU > thresh with precomputed areas; bit-identical op order to reference
__device__ inline bool iou_over2(const float4 a, float areaA, const float4 b, float areaB) {
#pragma clang fp contract(off)
    float ltx = fmaxf(a.x, b.x);
    float lty = fmaxf(a.y, b.y);
    float rbx = fminf(a.z, b.z);
    float rby = fminf(a.w, b.w);
    float w = fmaxf(rbx - ltx, 0.0f);
    float h = fmaxf(rby - lty, 0.0f);
    float inter = w * h;
    float iou = inter / (((areaA + areaB) - inter) + 1e-9f);
    return iou > NMS_T;
}

__device__ inline bool iou_over(const float4 a, float areaA, const float4 b) {
    float areaB = (b.z - b.x) * (b.w - b.y);
    return iou_over2(a, areaA, b, areaB);
}

// slice id -> (lvl, offset-in-level, length); uniform per block
__device__ inline void slice_map(int sid, int& lvl, int& loff, int& len) {
    if (sid < 48)      { lvl = 0; loff = sid * 4096;        len = 4096; }
    else if (sid < 60) { lvl = 1; loff = (sid - 48) * 4096; len = 4096; }
    else if (sid < 63) { lvl = 2; loff = (sid - 60) * 4096; len = 4096; }
    else if (sid == 63){ lvl = 3; loff = 0;                 len = 3072; }
    else               { lvl = 4; loff = 0;                 len = 768;  }
}

// ---------------------------------------------------------------------------
// Kernel 0: zero ghist + cand_cnt
// ---------------------------------------------------------------------------
__global__ __launch_bounds__(T_BLK) void zero_kernel(u32* __restrict__ dst) {
    for (int i = blockIdx.x * T_BLK + threadIdx.x; i < ZERO_WORDS; i += gridDim.x * T_BLK)
        dst[i] = 0u;
}

// ---------------------------------------------------------------------------
// Kernel A: distributed 13-bit score histogram per (img,lvl)
// ---------------------------------------------------------------------------
__global__ __launch_bounds__(T_BLK) void hist_kernel(
    const float* __restrict__ obj, u32* __restrict__ ghist)
{
    const int img = blockIdx.x / NSLICE;
    const int sid = blockIdx.x % NSLICE;
    int lvl, loff, len;
    slice_map(sid, lvl, loff, len);
    const int p = img * NLVL + lvl;
    const float* s = obj + (size_t)img * ATOT + LVL_OFF[lvl] + loff;
    const int tid = threadIdx.x;

    __shared__ u32 hist[NBIN];
    for (int b = tid; b < NBIN; b += T_BLK) hist[b] = 0u;
    __syncthreads();

    for (int i0 = tid * 4; i0 < len; i0 += T_BLK * 4) {
        float4 v = *(const float4*)(s + i0);
        atomicAdd(&hist[ordf(v.x) >> 19], 1u);
        atomicAdd(&hist[ordf(v.y) >> 19], 1u);
        atomicAdd(&hist[ordf(v.z) >> 19], 1u);
        atomicAdd(&hist[ordf(v.w) >> 19], 1u);
    }
    __syncthreads();

    u32* gh = ghist + (size_t)p * NBIN;
    for (int b = tid; b < NBIN; b += T_BLK) {
        u32 v = hist[b];
        if (v) atomicAdd(&gh[b], v);
    }
}

// ---------------------------------------------------------------------------
// Kernel B: boundary bin per problem.  b* = max b with count(digit >= b) >= k.
// ---------------------------------------------------------------------------
__global__ __launch_bounds__(T_BLK) void bound_kernel(
    const u32* __restrict__ ghist, u32* __restrict__ gbound)
{
    const int p   = blockIdx.x;
    const int lvl = p % NLVL;
    const u32 k   = (u32)LVL_K[lvl];
    const u32* gh = ghist + (size_t)p * NBIN;
    const int tid = threadIdx.x;

    u32 ch = 0;
    for (int b = tid * 32; b < tid * 32 + 32; ++b) ch += gh[b];

    __shared__ u32 suf[T_BLK];
    suf[tid] = ch;
    __syncthreads();
    for (int d = 1; d < T_BLK; d <<= 1) {
        u32 add = (tid + d < T_BLK) ? suf[tid + d] : 0u;
        __syncthreads();
        suf[tid] += add;
        __syncthreads();
    }
    const u32 inc = suf[tid];                    // count(digit >= tid*32)
    if (inc >= k && inc - ch < k) {              // boundary chunk: exactly one thread
        u32 cum = inc - ch;                      // count above this chunk
        int bin = tid * 32;
        for (int b = tid * 32 + 31; b >= tid * 32; --b) {
            u32 hb = gh[b];
            if (cum + hb >= k) { bin = b; break; }
            cum += hb;
        }
        gbound[p] = (u32)bin;
    }
}

// ---------------------------------------------------------------------------
// Kernel C: compact candidate keys (digit >= boundary bin); wave-aggregated
// atomics (1 atomicAdd per wave instead of per item).
// ---------------------------------------------------------------------------
__global__ __launch_bounds__(T_BLK) void compact_kernel(
    const float* __restrict__ obj, const u32* __restrict__ gbound,
    u32* __restrict__ cand_cnt, u64* __restrict__ cand)
{
    const int img = blockIdx.x / NSLICE;
    const int sid = blockIdx.x % NSLICE;
    int lvl, loff, len;
    slice_map(sid, lvl, loff, len);
    const int p = img * NLVL + lvl;
    const u32 bin = gbound[p];
    const float* s = obj + (size_t)img * ATOT + LVL_OFF[lvl] + loff;
    const int tid  = threadIdx.x;
    const int lane = tid & 63;
    u64* cp = cand + (size_t)p * CANDCAP;

    const u64 below = (lane == 0) ? 0ull : (~0ull >> (64 - lane));

    for (int i0 = tid * 4; i0 < len; i0 += T_BLK * 4) {
        float4 v = *(const float4*)(s + i0);
        float vv[4] = {v.x, v.y, v.z, v.w};
        bool ps[4];
        #pragma unroll
        for (int q = 0; q < 4; ++q) ps[q] = (ordf(vv[q]) >> 19) >= bin;
        u64 b0 = __ballot(ps[0]);
        u64 b1 = __ballot(ps[1]);
        u64 b2 = __ballot(ps[2]);
        u64 b3 = __ballot(ps[3]);
        int c0 = __popcll(b0), c1 = __popcll(b1), c2 = __popcll(b2), c3 = __popcll(b3);
        int tot = c0 + c1 + c2 + c3;
        if (tot == 0) continue;                  // wave-uniform
        u32 base_ = 0;
        if (lane == 0) base_ = atomicAdd(&cand_cnt[p], (u32)tot);
        base_ = (u32)__shfl((int)base_, 0);
        int o0 = (int)base_ + __popcll(b0 & below);
        int o1 = (int)base_ + c0 + __popcll(b1 & below);
        int o2 = (int)base_ + c0 + c1 + __popcll(b2 & below);
        int o3 = (int)base_ + c0 + c1 + c2 + __popcll(b3 & below);
        if (ps[0] && o0 < CANDCAP) cp[o0] = make_key(vv[0], loff + i0 + 0);
        if (ps[1] && o1 < CANDCAP) cp[o1] = make_key(vv[1], loff + i0 + 1);
        if (ps[2] && o2 < CANDCAP) cp[o2] = make_key(vv[2], loff + i0 + 2);
        if (ps[3] && o3 < CANDCAP) cp[o3] = make_key(vv[3], loff + i0 + 3);
    }
}

// ---------------------------------------------------------------------------
// Kernel D: per-problem exact top-k (bitonic over candidates) + decode + clip
// ---------------------------------------------------------------------------
__global__ __launch_bounds__(T_BLK) void sort_decode_kernel(
    const float4* __restrict__ deltas, const float4* __restrict__ anchors,
    const u32* __restrict__ cand_cnt, const u64* __restrict__ cand,
    float4* __restrict__ boxes_ws, float* __restrict__ scores_ws)
{
    const int p   = blockIdx.x;
    const int img = p / NLVL;
    const int lvl = p % NLVL;
    const int k   = LVL_K[lvl];
    const int off = LVL_OFF[lvl];
    const int tid = threadIdx.x;
    const int cnt = min((int)cand_cnt[p], CANDCAP);
    const u64* cp = cand + (size_t)p * CANDCAP;

    __shared__ u64 buf[CANDCAP];
    for (int i = tid; i < CANDCAP; i += T_BLK) buf[i] = (i < cnt) ? cp[i] : 0ull;
    __syncthreads();

    // bitonic sort ascending over CANDCAP elements (keys distinct, 0-padded)
    for (int sz = 2; sz <= CANDCAP; sz <<= 1) {
        for (int st = sz >> 1; st > 0; st >>= 1) {
            for (int i = tid; i < CANDCAP; i += T_BLK) {
                int j = i ^ st;
                if (j > i) {
                    u64 a = buf[i];
                    u64 b = buf[j];
                    bool up = ((i & sz) == 0);
                    if ((a > b) == up) { buf[i] = b; buf[j] = a; }
                }
            }
            __syncthreads();
        }
    }

    const size_t outbase = (size_t)img * TOTK + CAT_OFF[lvl];
    for (int r = tid; r < k; r += T_BLK) {
        u64 kk = buf[CANDCAP - 1 - r];
        int li = (int)(0xFFFFFFFFu - (unsigned)(kk & 0xFFFFFFFFull));
        int g  = off + li;
        u32 hu = (u32)(kk >> 32);                // bit-exact score recovery
        u32 fu = (hu & 0x80000000u) ? (hu ^ 0x80000000u) : ~hu;
        float sc = __uint_as_float(fu);
        float4 an = anchors[g];
        float4 dl = deltas[(size_t)img * ATOT + g];
        boxes_ws[outbase + r]  = decode_clip(an, dl);
        scores_ws[outbase + r] = sc;
    }
}

// ---------------------------------------------------------------------------
// Kernel 2a: pairwise IoU>thresh bitmask, 64x64 tiles (balanced), columns in
// registers, coalesced writes. Mask layout: mask[p][w][i] (word-major),
// word w bit l  <=>  IoU(box_i, box_{w*64+l}) > 0.7, for j > i.
// Block = 256 threads = 4 waves x 16 rows; one block per (rt, ct>=rt) tile.
// ---------------------------------------------------------------------------
__global__ __launch_bounds__(T_BLK) void nms_mask_kernel(
    const float4* __restrict__ boxes_ws, u64* __restrict__ mask)
{
    const int p   = blockIdx.x / MAXT;
    const int t   = blockIdx.x % MAXT;
    const int img = p / NLVL;
    const int lvl = p % NLVL;
    const int K   = LVL_K[lvl];
    const int W   = (K + 63) >> 6;
    const int T   = (W * (W + 1)) >> 1;
    if (t >= T) return;                   // uniform across block

    // triangular decode: tile (rt, ct), ct >= rt
    int rt = 0, acc = 0;
    while (acc + (W - rt) <= t) { acc += (W - rt); ++rt; }
    const int ct = rt + (t - acc);

    const int lane = threadIdx.x & 63;
    const int wv   = threadIdx.x >> 6;
    const size_t base = (size_t)img * TOTK + CAT_OFF[lvl];

    __shared__ float4 rowb[64];
    __shared__ u64    om[64];

    if (threadIdx.x < 64) {
        int i = rt * 64 + threadIdx.x;
        rowb[threadIdx.x] = (i < K) ? boxes_ws[base + i] : make_float4(0.f, 0.f, 0.f, 0.f);
    }
    __syncthreads();

    const int j = ct * 64 + lane;
    const bool jv = (j < K);
    const float4 bj = jv ? boxes_ws[base + j] : make_float4(0.f, 0.f, 0.f, 0.f);
    const float areaB = (bj.z - bj.x) * (bj.w - bj.y);

    #pragma unroll 4
    for (int r = 0; r < 16; ++r) {
        const int ri = wv * 16 + r;
        const int i  = rt * 64 + ri;
        if (i >= K) break;                // wave-uniform
        const float4 bi = rowb[ri];
        const float areaA = (bi.z - bi.x) * (bi.w - bi.y);
        bool over = jv & (j > i) & iou_over2(bi, areaA, bj, areaB);
        u64 m = __ballot(over);
        if (lane == 0) om[ri] = m;
    }
    __syncthreads();

    if (threadIdx.x < 64) {
        int i = rt * 64 + threadIdx.x;
        if (i < K)
            mask[(size_t)p * MW * MAXK + (size_t)ct * MAXK + i] = om[threadIdx.x];
    }
}

// ---------------------------------------------------------------------------
// Kernel 2b: serial greedy scan over precomputed mask. One wave per problem.
// Word-major layout: lane l streams mask[p][l][i] unit-stride over i.
// Groups of 16 rows: (1) hoist the 16 in-word diagonal words to SGPRs via
// readlane (independent of the serial state); (2) scalar-only serial
// resolution on one uniform u64; (3) parallel OR of kept rows into the
// distributed suppression words. Ping-pong banks, 32-row prefetch.
// ---------------------------------------------------------------------------
__global__ __launch_bounds__(64) void nms_scan_kernel(
    const u64* __restrict__ mask, float* __restrict__ scores_ws)
{
    const int p   = blockIdx.x;
    const int img = p / NLVL;
    const int lvl = p % NLVL;
    const int K   = LVL_K[lvl];
    const int W   = (K + 63) >> 6;
    const int lane = threadIdx.x;
    const u64* rowp = mask + (size_t)p * MW * MAXK + (size_t)lane * MAXK;

    u32 slo = 0u, shi = 0u;   // lane l: suppression bits [64l,64l+32) / [64l+32,64l+64)

#define ROWS16(X) X(0) X(1) X(2) X(3) X(4) X(5) X(6) X(7) \
                  X(8) X(9) X(10) X(11) X(12) X(13) X(14) X(15)

#define DECLA(j) u64 A##j;
#define DECLB(j) u64 B##j;
    ROWS16(DECLA) ROWS16(DECLB)

#define LDROWI(i) ((lane < MW) ? rowp[(((i) < K) ? (i) : (K - 1))] : 0ull)
#define LDA(j) A##j = LDROWI(rb + j);
#define LDB(j) B##j = LDROWI(rb + j);

    { const int rb = 0;  ROWS16(LDA) }
    { const int rb = 16; ROWS16(LDB) }

#define SDA(j) const u64 sd##j = rl64(A##j, wc);
#define SDB(j) const u64 sd##j = rl64(B##j, wc);
#define SR(j)  if (!((sw >> (bb + (j))) & 1ull)) { sw |= sd##j; kb |= (1u << (j)); }
#define ORA(j) acc |= (0ull - (u64)((kb >> (j)) & 1u)) & A##j;
#define ORB(j) acc |= (0ull - (u64)((kb >> (j)) & 1u)) & B##j;

#define PROC(SDX, ORX, LDX) {                                                \
        const int rowbase = g * 16;                                          \
        const int wc = rowbase >> 6;                                         \
        const int bb = rowbase & 63;                                         \
        u64 sw = (((u64)(u32)__builtin_amdgcn_readlane((int)shi, wc)) << 32) \
               |  ((u64)(u32)__builtin_amdgcn_readlane((int)slo, wc));       \
        ROWS16(SDX)                                                          \
        u32 kb = 0u;                                                         \
        ROWS16(SR)                                                           \
        const u64 lanesel = (lane >= wc && lane < MW) ? ~0ull : 0ull;        \
        u64 acc = 0ull;                                                      \
        ROWS16(ORX)                                                          \
        acc &= lanesel;                                                      \
        slo |= (u32)acc;                                                     \
        shi |= (u32)(acc >> 32);                                             \
        const int rb = rowbase + 32;                                         \
        ROWS16(LDX) }

    const int ng = K >> 4;               // 125 (K=2000) or 48 (K=768)
    for (int g = 0; g < ng; ++g) {
        if ((g & 1) == 0) { PROC(SDA, ORA, LDA) }
        else              { PROC(SDB, ORB, LDB) }
    }

#undef PROC
#undef ORB
#undef ORA
#undef SR
#undef SDB
#undef SDA
#undef LDB
#undef LDA
#undef LDROWI
#undef DECLB
#undef DECLA
#undef ROWS16

    const size_t base = (size_t)img * TOTK + CAT_OFF[lvl];
    for (int c = 0; c < W; ++c) {
        u32 wlo = (u32)__shfl((int)slo, c);
        u32 whi = (u32)__shfl((int)shi, c);
        u64 w = (((u64)whi) << 32) | (u64)wlo;
        int r = c * 64 + lane;
        if (r < K && ((w >> lane) & 1ull)) scores_ws[base + r] = NEGV;
    }
}

// ---------------------------------------------------------------------------
// Kernel 2 (fallback, ws too small): single-wave greedy NMS (proven correct)
// ---------------------------------------------------------------------------
__global__ __launch_bounds__(64) void nms_kernel(
    const float4* __restrict__ boxes_ws, float* __restrict__ scores_ws)
{
    const int img = blockIdx.x / NLVL;
    const int lvl = blockIdx.x % NLVL;
    const int K   = LVL_K[lvl];
    const size_t base = (size_t)img * TOTK + CAT_OFF[lvl];
    const int lane = threadIdx.x;

    __shared__ float4 bs[MAXK];
    for (int i = lane; i < K; i += 64) bs[i] = boxes_ws[base + i];
    __syncthreads();

    u64 myw = 0ull;
    for (int i = 0; i < K; ++i) {
        u64 wi = __shfl(myw, i >> 6);
        bool suppressed = (wi >> (i & 63)) & 1ull;
        if (!suppressed) {
            float4 bi = bs[i];
            float areaA = (bi.z - bi.x) * (bi.w - bi.y);
            for (int jb = i + 1; jb < K; jb += 64) {
                int j = jb + lane;
                bool over = false;
                if (j < K) over = iou_over(bi, areaA, bs[j]);
                u64 m = __ballot(over);
                int w0 = jb >> 6;
                int sh = jb & 63;
                if (lane == w0) myw |= (m << sh);
                if (sh && lane == (w0 + 1)) myw |= (m >> (64 - sh));
            }
        }
    }
    const int nch = (K + 63) >> 6;
    for (int c = 0; c < nch; ++c) {
        u64 w = __shfl(myw, c);
        int r = c * 64 + lane;
        if (r < K && ((w >> lane) & 1ull)) scores_ws[base + r] = NEGV;
    }
}

// ---------------------------------------------------------------------------
// final_topk: per-image exact top-1000 (proven code, unchanged)
// ---------------------------------------------------------------------------
__device__ void radix_topk_sorted(const float* __restrict__ s, int n, int k, int P,
                                  u32* hist, u32* chunk, u64* buf, u64* bcast, int* ibcast)
{
    const int tid = threadIdx.x;
    const int wid = tid >> 6;
    u64 pref = 0ull;
    int remk = k;
    int done = 0;
    const int SH[6] = {53, 42, 31, 20, 9, 0};
    const int WD[6] = {11, 11, 11, 11, 11, 9};

    for (int pass = 0; pass < 6 && !done; ++pass) {
        const int shift = SH[pass];
        const int nb    = 1 << WD[pass];
        for (int b = tid; b < 4 * 2048; b += T_BLK) hist[b] = 0u;
        __syncthreads();
        const u64 himask = (pass == 0) ? 0ull : (~0ull << SH[pass - 1]);
        u32* myh = hist + wid * 2048;
        for (int i0 = tid * 4; i0 < n; i0 += T_BLK * 4) {
            float4 v = *(const float4*)(s + i0);
            u64 k0 = make_key(v.x, i0);
            u64 k1 = make_key(v.y, i0 + 1);
            u64 k2 = make_key(v.z, i0 + 2);
            u64 k3 = make_key(v.w, i0 + 3);
            if ((k0 & himask) == pref) atomicAdd(&myh[(u32)(k0 >> shift) & (nb - 1)], 1u);
            if ((k1 & himask) == pref) atomicAdd(&myh[(u32)(k1 >> shift) & (nb - 1)], 1u);
            if ((k2 & himask) == pref) atomicAdd(&myh[(u32)(k2 >> shift) & (nb - 1)], 1u);
            if ((k3 & himask) == pref) atomicAdd(&myh[(u32)(k3 >> shift) & (nb - 1)], 1u);
        }
        __syncthreads();
        u32 csum = 0;
        for (int b = tid * 8; b < tid * 8 + 8; ++b)
            if (b < nb) csum += hist[b] + hist[2048 + b] + hist[4096 + b] + hist[6144 + b];
        chunk[tid] = csum;
        __syncthreads();
        if (tid == 0) {
            int cum = 0, cidx = 0;
            for (int c = 255; c >= 0; --c) {
                int cs = (int)chunk[c];
                if (cum + cs >= remk) { cidx = c; break; }
                cum += cs;
            }
            for (int b = cidx * 8 + 7; b >= cidx * 8; --b) {
                if (b >= nb) continue;
                int cb = (int)(hist[b] + hist[2048 + b] + hist[4096 + b] + hist[6144 + b]);
                if (cum + cb >= remk) {
                    bcast[0]  = pref | (((u64)(u32)b) << shift);
                    ibcast[0] = remk - cum;
                    ibcast[1] = (cb == (remk - cum)) ? 1 : 0;
                    break;
                }
                cum += cb;
            }
        }
        __syncthreads();
        pref = bcast[0];
        remk = ibcast[0];
        done = ibcast[1];
        __syncthreads();
    }
    const u64 thresh = pref;

    if (tid == 0) ibcast[2] = 0;
    __syncthreads();
    for (int i0 = tid * 4; i0 < n; i0 += T_BLK * 4) {
        float4 v = *(const float4*)(s + i0);
        u64 kk[4] = { make_key(v.x, i0), make_key(v.y, i0 + 1),
                      make_key(v.z, i0 + 2), make_key(v.w, i0 + 3) };
        #pragma unroll
        for (int q = 0; q < 4; ++q) {
            if (kk[q] >= thresh) {
                int pos = atomicAdd(&ibcast[2], 1);
                if (pos < P) buf[pos] = kk[q];
            }
        }
    }
    __syncthreads();
    for (int i = k + tid; i < P; i += T_BLK) buf[i] = 0ull;
    __syncthreads();

    for (int sz = 2; sz <= P; sz <<= 1) {
        for (int st = sz >> 1; st > 0; st >>= 1) {
            for (int i = tid; i < P; i += T_BLK) {
                int j = i ^ st;
                if (j > i) {
                    u64 a = buf[i];
                    u64 b = buf[j];
                    bool up = ((i & sz) == 0);
                    if ((a > b) == up) { buf[i] = b; buf[j] = a; }
                }
            }
            __syncthreads();
        }
    }
}

__global__ __launch_bounds__(T_BLK) void final_topk_kernel(
    const float4* __restrict__ boxes_ws, const float* __restrict__ scores_ws,
    float* __restrict__ out)
{
    const int img = blockIdx.x;
    const float* s = scores_ws + (size_t)img * TOTK;

    __shared__ u32 hist[4 * 2048];
    __shared__ u32 chunk[256];
    __shared__ u64 buf[1024];
    __shared__ u64 bcast;
    __shared__ int ibcast[4];

    radix_topk_sorted(s, TOTK, FINAL_K, 1024, hist, chunk, buf, &bcast, ibcast);

    const int tid = threadIdx.x;
    float4* outb = (float4*)out;               // fboxes: [16][1000][4]
    float*  outs = out + NIMG * FINAL_K * 4;   // fscores: [16][1000]
    for (int r = tid; r < FINAL_K; r += T_BLK) {
        u64 kk = buf[1024 - 1 - r];
        int idx = (int)(0xFFFFFFFFu - (unsigned)(kk & 0xFFFFFFFFull));
        outb[img * FINAL_K + r] = boxes_ws[(size_t)img * TOTK + idx];
        outs[img * FINAL_K + r] = s[idx];
    }
}

// ---------------------------------------------------------------------------
extern "C" void kernel_launch(void* const* d_in, const int* in_sizes, int n_in,
                              void* d_out, int out_size, void* d_ws, size_t ws_size,
                              hipStream_t stream)
{
    const float*  obj     = (const float*)d_in[0];
    const float4* deltas  = (const float4*)d_in[1];
    const float4* anchors = (const float4*)d_in[2];
    float* out = (float*)d_out;

    char* ws = (char*)d_ws;
    float4* boxes_ws  = (float4*)(ws + BOX_OFF);
    float*  scores_ws = (float*)(ws + SCORES_OFF);
    u32*    ghist     = (u32*)(ws + GHIST_OFF);
    u32*    cand_cnt  = (u32*)(ws + CNT_OFF);
    u32*    gbound    = (u32*)(ws + GB_OFF);
    u64*    cand      = (u64*)(ws + CAND_OFF);

    zero_kernel<<<512, T_BLK, 0, stream>>>(ghist);   // ghist + cand_cnt contiguous
    hist_kernel<<<NIMG * NSLICE, T_BLK, 0, stream>>>(obj, ghist);
    bound_kernel<<<NIMG * NLVL, T_BLK, 0, stream>>>(ghist, gbound);
    compact_kernel<<<NIMG * NSLICE, T_BLK, 0, stream>>>(obj, gbound, cand_cnt, cand);
    sort_decode_kernel<<<NIMG * NLVL, T_BLK, 0, stream>>>(deltas, anchors, cand_cnt, cand,
                                                          boxes_ws, scores_ws);

    if (ws_size >= MASK_OFF + MASK_BYTES) {
        u64* mask = (u64*)(ws + MASK_OFF);
        nms_mask_kernel<<<NIMG * NLVL * MAXT, T_BLK, 0, stream>>>(boxes_ws, mask);
        nms_scan_kernel<<<NIMG * NLVL, 64, 0, stream>>>(mask, scores_ws);
    } else {
        nms_kernel<<<NIMG * NLVL, 64, 0, stream>>>(boxes_ws, scores_ws);
    }

    final_topk_kernel<<<NIMG, T_BLK, 0, stream>>>(boxes_ws, scores_ws, out);
}